// Round 1
// baseline (303.603 us; speedup 1.0000x reference)
//
#include <hip/hip_runtime.h>

// LightGlue attention block: B=4, N=4096, D=256.
//   q = desc0@Wq^T+bq; k,v = desc1@{Wk,Wv}^T+{bk,bv}
//   att = softmax(q k^T / 16) v ; out = att@Wo^T + bo
// ws layout (bytes): q[0,8M) k[8M,16M) vT[16M,24M) att[24M,32M)  (needs 32MB)

typedef __attribute__((ext_vector_type(8))) __bf16 bf16x8;
typedef __attribute__((ext_vector_type(4))) float f32x4;
typedef __attribute__((ext_vector_type(4))) unsigned int u32x4;
typedef __attribute__((ext_vector_type(4))) unsigned short us16x4;

__device__ __forceinline__ unsigned short f2bf(float f) {
  unsigned u = __builtin_bit_cast(unsigned, f);
  u += 0x7FFFu + ((u >> 16) & 1u);   // RNE
  return (unsigned short)(u >> 16);
}
__device__ __forceinline__ unsigned pk2(float a, float b) {
  return (unsigned)f2bf(a) | ((unsigned)f2bf(b) << 16);
}
__device__ __forceinline__ int swz4(int r) { return (r ^ (r >> 2)) & 3; }  // latin-square 2-bit swizzle
__device__ __forceinline__ bf16x8 ldbf16(const void* p) {
  return __builtin_bit_cast(bf16x8, *(const u32x4*)p);
}
__device__ __forceinline__ f32x4 mfma16(bf16x8 a, bf16x8 b, f32x4 c) {
  return __builtin_amdgcn_mfma_f32_16x16x32_bf16(a, b, c, 0, 0, 0);
}

// ---------------- projection GEMM: C[16384,256] = A @ W^T + bias ----------------
// IN_BF16: 0 = A is f32 (desc), 1 = A is bf16 (att)
// MODE: 0 = bf16 row-major; 1 = bf16 transposed [b][256][4096]; 2 = f32 row-major
template <int IN_BF16, int MODE>
__global__ __launch_bounds__(256, 1) void proj_k(const void* __restrict__ Ain,
                                                 const float* __restrict__ W,
                                                 const float* __restrict__ bias,
                                                 void* __restrict__ Cout) {
  __shared__ __align__(16) unsigned short Wl[256 * 32];  // W chunk [256 j][32 k] bf16, swizzled
  __shared__ __align__(16) unsigned short Al[64 * 32];   // A chunk [64 row][32 k] bf16, swizzled
  __shared__ float biasl[256];
  const int tid = threadIdx.x;
  const int w = tid >> 6, l = tid & 63, g = l >> 4, c = l & 15;
  const int row0 = blockIdx.x * 64;
  biasl[tid] = bias[tid];

  f32x4 acc[16];
#pragma unroll
  for (int jt = 0; jt < 16; ++jt) acc[jt] = (f32x4){0.f, 0.f, 0.f, 0.f};

#pragma unroll 1
  for (int ch = 0; ch < 8; ++ch) {
    __syncthreads();
    {  // stage W: thread = row j, 4 blocks of 8 f32 -> bf16x8
      const float* wp = W + tid * 256 + ch * 32;
      const int sw = swz4(tid);
#pragma unroll
      for (int bl = 0; bl < 4; ++bl) {
        float4 x = *(const float4*)(wp + bl * 8);
        float4 y = *(const float4*)(wp + bl * 8 + 4);
        u32x4 v;
        v[0] = pk2(x.x, x.y); v[1] = pk2(x.z, x.w);
        v[2] = pk2(y.x, y.y); v[3] = pk2(y.z, y.w);
        *(u32x4*)&Wl[tid * 32 + ((bl ^ sw) << 3)] = v;
      }
    }
    {  // stage A: row = tid>>2, block = tid&3
      const int r = tid >> 2, bl = tid & 3;
      const int sw = swz4(r);
      if (IN_BF16) {
        const unsigned short* ap =
            (const unsigned short*)Ain + (size_t)(row0 + r) * 256 + ch * 32 + bl * 8;
        *(u32x4*)&Al[r * 32 + ((bl ^ sw) << 3)] = *(const u32x4*)ap;
      } else {
        const float* ap = (const float*)Ain + (size_t)(row0 + r) * 256 + ch * 32 + bl * 8;
        float4 x = *(const float4*)(ap);
        float4 y = *(const float4*)(ap + 4);
        u32x4 v;
        v[0] = pk2(x.x, x.y); v[1] = pk2(x.z, x.w);
        v[2] = pk2(y.x, y.y); v[3] = pk2(y.z, y.w);
        *(u32x4*)&Al[r * 32 + ((bl ^ sw) << 3)] = v;
      }
    }
    __syncthreads();
    const int ra = w * 16 + c;
    bf16x8 af = ldbf16(&Al[ra * 32 + ((g ^ swz4(ra)) << 3)]);
#pragma unroll
    for (int jt = 0; jt < 16; ++jt) {
      const int col = jt * 16 + c;
      bf16x8 bfr = ldbf16(&Wl[col * 32 + ((g ^ swz4(col)) << 3)]);
      acc[jt] = mfma16(af, bfr, acc[jt]);  // C/D: col=lane&15, row=4*(lane>>4)+r
    }
  }

#pragma unroll
  for (int jt = 0; jt < 16; ++jt) {
    const int col = jt * 16 + c;
    const float bv = biasl[col];
    const int rloc = w * 16 + (g << 2);
    if (MODE == 0) {
      unsigned short* q = (unsigned short*)Cout;
#pragma unroll
      for (int r = 0; r < 4; ++r)
        q[(size_t)(row0 + rloc + r) * 256 + col] = f2bf(acc[jt][r] + bv);
    } else if (MODE == 1) {
      unsigned short* vt = (unsigned short*)Cout;
      const int n = row0 + rloc;
      const int b = n >> 12, nl = n & 4095;
      us16x4 pk;
      pk[0] = f2bf(acc[jt][0] + bv); pk[1] = f2bf(acc[jt][1] + bv);
      pk[2] = f2bf(acc[jt][2] + bv); pk[3] = f2bf(acc[jt][3] + bv);
      *(us16x4*)(vt + (size_t)(b * 256 + col) * 4096 + nl) = pk;  // 4 consecutive n, 8B store
    } else {
      float* o = (float*)Cout;
#pragma unroll
      for (int r = 0; r < 4; ++r)
        o[(size_t)(row0 + rloc + r) * 256 + col] = acc[jt][r] + bv;
    }
  }
}

// ---------------- flash attention ----------------
// 256 blocks x 256 thr (4 waves). Block = 64 q-rows (16/wave). KVBLK=32, dbuf LDS.
// Swapped QK^T: S^T=K·Q^T  (softmax state lane-local at q=lane&15)
// Swapped PV:   O^T=V^T·P  (O layout col=q matches state; contiguous att stores)
__device__ __forceinline__ void attn_load(const unsigned short* kb, const unsigned short* vtb,
                                          int kv0, int tid, u32x4* kr, u32x4* vr) {
#pragma unroll
  for (int i = 0; i < 4; ++i) {
    const int slot = tid + i * 256;
    const int kk = slot >> 5, bl = slot & 31;
    kr[i] = *(const u32x4*)(kb + (size_t)(kv0 + kk) * 256 + bl * 8);
  }
#pragma unroll
  for (int i = 0; i < 4; ++i) {
    const int slot = tid + i * 256;
    const int d = slot >> 2, bl = slot & 3;
    vr[i] = *(const u32x4*)(vtb + (size_t)d * 4096 + kv0 + bl * 8);
  }
}
__device__ __forceinline__ void attn_store(unsigned char* smem, int buf, int tid,
                                           const u32x4* kr, const u32x4* vr) {
  unsigned char* Kb = smem + buf * 16384;
  unsigned char* Vb = smem + 32768 + buf * 16384;
#pragma unroll
  for (int i = 0; i < 4; ++i) {
    const int slot = tid + i * 256;
    const int kk = slot >> 5, bl = slot & 31;
    *(u32x4*)(Kb + kk * 512 + ((bl ^ (kk & 7)) << 4)) = kr[i];  // G4 XOR swizzle
  }
#pragma unroll
  for (int i = 0; i < 4; ++i) {
    const int slot = tid + i * 256;
    const int d = slot >> 2, bl = slot & 3;
    *(u32x4*)(Vb + d * 64 + ((bl ^ swz4(d)) << 4)) = vr[i];
  }
}

__global__ __launch_bounds__(256, 1) void attn_k(const unsigned short* __restrict__ qg,
                                                 const unsigned short* __restrict__ kg,
                                                 const unsigned short* __restrict__ vtg,
                                                 unsigned short* __restrict__ og) {
  __shared__ __align__(16) unsigned char smem[69632];  // K 2x16K | Vt 2x16K | P 4x1K
  const int tid = threadIdx.x, w = tid >> 6, l = tid & 63, g = l >> 4, c = l & 15;
  const int bid = blockIdx.x;
  const int qt = (bid & 7) * 32 + (bid >> 3);  // XCD-bijective swizzle (256 = 8*32)
  const int b4 = qt >> 6;
  const int q0 = (qt & 63) * 64;
  const size_t qrow = (size_t)b4 * 4096 + q0 + w * 16 + c;

  u32x4 qf[8];  // Q^T B-frags: Q[q=c][ch*32 + 8g + j]
  {
    const unsigned short* qp = qg + qrow * 256;
#pragma unroll
    for (int ch = 0; ch < 8; ++ch) qf[ch] = *(const u32x4*)(qp + ch * 32 + g * 8);
  }
  f32x4 o[16];
#pragma unroll
  for (int dt = 0; dt < 16; ++dt) o[dt] = (f32x4){0.f, 0.f, 0.f, 0.f};
  float m_run = -1e30f, l_run = 0.f;

  const unsigned short* kb = kg + (size_t)b4 * 4096 * 256;
  const unsigned short* vtb = vtg + (size_t)b4 * 256 * 4096;
  u32x4 kr[4], vr[4];
  attn_load(kb, vtb, 0, tid, kr, vr);
  attn_store(smem, 0, tid, kr, vr);
  __syncthreads();

  const float alpha = 0.09016844f;  // log2(e)/sqrt(256)
  unsigned char* Pb = smem + 65536 + w * 1024;
  const int spc = swz4(c);

#pragma unroll 1
  for (int t = 0; t < 128; ++t) {
    const int cur = t & 1;
    if (t + 1 < 128) attn_load(kb, vtb, (t + 1) * 32, tid, kr, vr);  // hide under compute
    const unsigned char* Kb = smem + cur * 16384;
    const unsigned char* Vb = smem + 32768 + cur * 16384;

    // S^T = K · Q^T : A=K rows (LDS), B=Q^T (regs). D: row=kk(4g+r), col=q(c)
    f32x4 s0 = {0.f, 0.f, 0.f, 0.f}, s1 = {0.f, 0.f, 0.f, 0.f};
#pragma unroll
    for (int ch = 0; ch < 8; ++ch) {
      const int blk = (ch << 2) | g;
      bf16x8 a0 = ldbf16(Kb + c * 512 + ((blk ^ (c & 7)) << 4));
      bf16x8 a1 = ldbf16(Kb + (16 + c) * 512 + ((blk ^ (c & 7)) << 4));
      bf16x8 bq = __builtin_bit_cast(bf16x8, qf[ch]);
      s0 = mfma16(a0, bq, s0);
      s1 = mfma16(a1, bq, s1);
    }
    // online softmax over kk (all values this lane holds share q=c)
    float sv[8];
#pragma unroll
    for (int r = 0; r < 4; ++r) { sv[r] = s0[r] * alpha; sv[4 + r] = s1[r] * alpha; }
    float mt = sv[0];
#pragma unroll
    for (int i = 1; i < 8; ++i) mt = fmaxf(mt, sv[i]);
    mt = fmaxf(mt, __shfl_xor(mt, 16));
    mt = fmaxf(mt, __shfl_xor(mt, 32));
    if (__any(mt > m_run + 8.f)) {  // defer-max (T13)
      const float mn = fmaxf(m_run, mt);
      const float f = exp2f(m_run - mn);
      l_run *= f;
#pragma unroll
      for (int dt = 0; dt < 16; ++dt) {
        o[dt][0] *= f; o[dt][1] *= f; o[dt][2] *= f; o[dt][3] *= f;
      }
      m_run = mn;
    }
    float p[8], ls = 0.f;
#pragma unroll
    for (int i = 0; i < 8; ++i) { p[i] = exp2f(sv[i] - m_run); ls += p[i]; }
    ls += __shfl_xor(ls, 16);
    ls += __shfl_xor(ls, 32);
    l_run += ls;

    // P -> LDS [q=16][kk=32] bf16 (per-wave region, intra-wave RAW only)
    us16x4 w0, w1;
    w0[0] = f2bf(p[0]); w0[1] = f2bf(p[1]); w0[2] = f2bf(p[2]); w0[3] = f2bf(p[3]);
    w1[0] = f2bf(p[4]); w1[1] = f2bf(p[5]); w1[2] = f2bf(p[6]); w1[3] = f2bf(p[7]);
    *(us16x4*)(Pb + c * 64 + (((g >> 1) ^ spc) << 4) + ((g & 1) << 3)) = w0;
    *(us16x4*)(Pb + c * 64 + (((2 + (g >> 1)) ^ spc) << 4) + ((g & 1) << 3)) = w1;
    bf16x8 bp = ldbf16(Pb + c * 64 + ((g ^ spc) << 4));  // B[kk=8g+j][q=c]

    // O^T += V^T · P : A=Vt rows d (LDS), B=P. D: row=d(4g+r), col=q(c)
#pragma unroll
    for (int dt = 0; dt < 16; ++dt) {
      const int d = dt * 16 + c;
      bf16x8 av = ldbf16(Vb + d * 64 + ((g ^ swz4(d)) << 4));
      o[dt] = mfma16(av, bp, o[dt]);
    }
    __syncthreads();
    if (t + 1 < 128) attn_store(smem, (t + 1) & 1, tid, kr, vr);
    __syncthreads();
  }
  const float inv = 1.f / l_run;  // l_run for q=c, matches O col layout
  unsigned short* op = og + qrow * 256;
#pragma unroll
  for (int dt = 0; dt < 16; ++dt) {
    us16x4 pk;
    pk[0] = f2bf(o[dt][0] * inv); pk[1] = f2bf(o[dt][1] * inv);
    pk[2] = f2bf(o[dt][2] * inv); pk[3] = f2bf(o[dt][3] * inv);
    *(us16x4*)(op + dt * 16 + (g << 2)) = pk;  // 4 consecutive d, 8B store
  }
}

extern "C" void kernel_launch(void* const* d_in, const int* in_sizes, int n_in,
                              void* d_out, int out_size, void* d_ws, size_t ws_size,
                              hipStream_t stream) {
  (void)in_sizes; (void)n_in; (void)out_size; (void)ws_size;
  const float* desc0 = (const float*)d_in[0];
  const float* desc1 = (const float*)d_in[1];
  const float* Wq = (const float*)d_in[2];
  const float* bq = (const float*)d_in[3];
  const float* Wk = (const float*)d_in[4];
  const float* bk = (const float*)d_in[5];
  const float* Wv = (const float*)d_in[6];
  const float* bv = (const float*)d_in[7];
  const float* Wo = (const float*)d_in[8];
  const float* bo = (const float*)d_in[9];

  unsigned char* ws = (unsigned char*)d_ws;
  unsigned short* qw = (unsigned short*)(ws);
  unsigned short* kw = (unsigned short*)(ws + 8388608);
  unsigned short* vtw = (unsigned short*)(ws + 16777216);
  unsigned short* aw = (unsigned short*)(ws + 25165824);

  proj_k<0, 0><<<256, 256, 0, stream>>>(desc0, Wq, bq, qw);
  proj_k<0, 0><<<256, 256, 0, stream>>>(desc1, Wk, bk, kw);
  proj_k<0, 1><<<256, 256, 0, stream>>>(desc1, Wv, bv, vtw);
  attn_k<<<256, 256, 0, stream>>>(qw, kw, vtw, aw);
  proj_k<1, 2><<<256, 256, 0, stream>>>(aw, Wo, bo, (float*)d_out);
}

// Round 2
// 163.305 us; speedup vs baseline: 1.8591x; 1.8591x over previous
//
#include <hip/hip_runtime.h>

// LightGlue attention block: B=4, N=4096, D=256.
//   q = desc0@Wq^T+bq; k,v = desc1@{Wk,Wv}^T+{bk,bv}
//   att = softmax(q k^T / 16) v ; out = att@Wo^T + bo
// ws layout (bytes): q[0,8M) k[8M,16M) vT[16M,24M) att[24M,32M)  (needs 32MB)

typedef __attribute__((ext_vector_type(8))) __bf16 bf16x8;
typedef __attribute__((ext_vector_type(4))) float f32x4;
typedef __attribute__((ext_vector_type(4))) unsigned int u32x4;
typedef __attribute__((ext_vector_type(4))) unsigned short us16x4;

__device__ __forceinline__ unsigned short f2bf(float f) {
  unsigned u = __builtin_bit_cast(unsigned, f);
  u += 0x7FFFu + ((u >> 16) & 1u);   // RNE
  return (unsigned short)(u >> 16);
}
__device__ __forceinline__ unsigned pk2(float a, float b) {
  return (unsigned)f2bf(a) | ((unsigned)f2bf(b) << 16);
}
__device__ __forceinline__ int swz4(int r) { return (r ^ (r >> 2)) & 3; }
__device__ __forceinline__ bf16x8 ldbf16(const void* p) {
  return __builtin_bit_cast(bf16x8, *(const u32x4*)p);
}
__device__ __forceinline__ f32x4 mfma16(bf16x8 a, bf16x8 b, f32x4 c) {
  return __builtin_amdgcn_mfma_f32_16x16x32_bf16(a, b, c, 0, 0, 0);
}
// async global->LDS, 16B per lane. LDS dest = wave-uniform base + lane*16 (linear).
__device__ __forceinline__ void gld16(void* lds, const void* gsrc) {
  __builtin_amdgcn_global_load_lds(
      (const __attribute__((address_space(1))) unsigned int*)gsrc,
      (__attribute__((address_space(3))) unsigned int*)lds, 16, 0, 0);
}

// ---------------- projection GEMM: C[16384, 64-col quarter] = A @ W^T + bias --------
// Grid 1024 = 256 M-tiles x 4 N-quarters. 256 thr (4 waves), 4 waves/SIMD.
// IN_BF16: 0 = A f32, 1 = A bf16.  MODE: 0 bf16 row-major; 1 bf16 [b][256][4096]; 2 f32.
template <int IN_BF16, int MODE>
__global__ __launch_bounds__(256, 4) void proj_k(const void* __restrict__ Ain,
                                                 const float* __restrict__ W,
                                                 const float* __restrict__ bias,
                                                 void* __restrict__ Cout) {
  __shared__ __align__(16) unsigned short Al[2][64 * 32];
  __shared__ __align__(16) unsigned short Wl[2][64 * 32];
  __shared__ float biasl[64];
  const int tid = threadIdx.x;
  const int w = tid >> 6, l = tid & 63, g = l >> 4, c = l & 15;
  const int mt = blockIdx.x & 255, nq = blockIdx.x >> 8;
  const int row0 = mt * 64, n0 = nq * 64;
  if (tid < 64) biasl[tid] = bias[n0 + tid];

  const int sr = tid >> 2, seg = tid & 3;  // staging: row 0..63, 8-elem segment 0..3
  const int ssw = swz4(sr);

  {  // prologue: stage chunk 0 -> buf 0
    if (IN_BF16) {
      const unsigned short* ap = (const unsigned short*)Ain + (size_t)(row0 + sr) * 256 + seg * 8;
      *(u32x4*)&Al[0][sr * 32 + ((seg ^ ssw) << 3)] = *(const u32x4*)ap;
    } else {
      const float* ap = (const float*)Ain + (size_t)(row0 + sr) * 256 + seg * 8;
      float4 x = *(const float4*)ap, y = *(const float4*)(ap + 4);
      u32x4 v; v[0] = pk2(x.x, x.y); v[1] = pk2(x.z, x.w); v[2] = pk2(y.x, y.y); v[3] = pk2(y.z, y.w);
      *(u32x4*)&Al[0][sr * 32 + ((seg ^ ssw) << 3)] = v;
    }
    const float* wp = W + (size_t)(n0 + sr) * 256 + seg * 8;
    float4 x = *(const float4*)wp, y = *(const float4*)(wp + 4);
    u32x4 v; v[0] = pk2(x.x, x.y); v[1] = pk2(x.z, x.w); v[2] = pk2(y.x, y.y); v[3] = pk2(y.z, y.w);
    *(u32x4*)&Wl[0][sr * 32 + ((seg ^ ssw) << 3)] = v;
  }
  __syncthreads();

  f32x4 acc[4];
#pragma unroll
  for (int jt = 0; jt < 4; ++jt) acc[jt] = (f32x4){0.f, 0.f, 0.f, 0.f};

#pragma unroll 1
  for (int ch = 0; ch < 8; ++ch) {
    const int cur = ch & 1;
    const bool pre = (ch + 1 < 8);
    float4 ax, ay, wx, wy; u32x4 abv;
    if (pre) {  // T14: issue loads for ch+1 early
      const int ko = (ch + 1) * 32 + seg * 8;
      if (IN_BF16) {
        abv = *(const u32x4*)((const unsigned short*)Ain + (size_t)(row0 + sr) * 256 + ko);
      } else {
        const float* ap = (const float*)Ain + (size_t)(row0 + sr) * 256 + ko;
        ax = *(const float4*)ap; ay = *(const float4*)(ap + 4);
      }
      const float* wp = W + (size_t)(n0 + sr) * 256 + ko;
      wx = *(const float4*)wp; wy = *(const float4*)(wp + 4);
    }
    const int ra = w * 16 + c;
    bf16x8 af = ldbf16(&Al[cur][ra * 32 + ((g ^ swz4(ra)) << 3)]);
#pragma unroll
    for (int jt = 0; jt < 4; ++jt) {
      const int j = jt * 16 + c;
      bf16x8 bfr = ldbf16(&Wl[cur][j * 32 + ((g ^ swz4(j)) << 3)]);
      acc[jt] = mfma16(af, bfr, acc[jt]);  // C/D: col=lane&15, row=4*(lane>>4)+r
    }
    if (pre) {  // convert + write late
      u32x4 v;
      if (IN_BF16) v = abv;
      else { v[0] = pk2(ax.x, ax.y); v[1] = pk2(ax.z, ax.w); v[2] = pk2(ay.x, ay.y); v[3] = pk2(ay.z, ay.w); }
      *(u32x4*)&Al[1 - cur][sr * 32 + ((seg ^ ssw) << 3)] = v;
      u32x4 vw; vw[0] = pk2(wx.x, wx.y); vw[1] = pk2(wx.z, wx.w); vw[2] = pk2(wy.x, wy.y); vw[3] = pk2(wy.z, wy.w);
      *(u32x4*)&Wl[1 - cur][sr * 32 + ((seg ^ ssw) << 3)] = vw;
    }
    __syncthreads();
  }

#pragma unroll
  for (int jt = 0; jt < 4; ++jt) {
    const int col = n0 + jt * 16 + c;
    const float bv = biasl[jt * 16 + c];
    const int rloc = w * 16 + (g << 2);
    if (MODE == 0) {
      unsigned short* q = (unsigned short*)Cout;
#pragma unroll
      for (int r = 0; r < 4; ++r)
        q[(size_t)(row0 + rloc + r) * 256 + col] = f2bf(acc[jt][r] + bv);
    } else if (MODE == 1) {
      unsigned short* vt = (unsigned short*)Cout;
      const int n = row0 + rloc;
      const int b = n >> 12, nl = n & 4095;
      us16x4 pk;
      pk[0] = f2bf(acc[jt][0] + bv); pk[1] = f2bf(acc[jt][1] + bv);
      pk[2] = f2bf(acc[jt][2] + bv); pk[3] = f2bf(acc[jt][3] + bv);
      *(us16x4*)(vt + (size_t)(b * 256 + col) * 4096 + nl) = pk;
    } else {
      float* o = (float*)Cout;
#pragma unroll
      for (int r = 0; r < 4; ++r)
        o[(size_t)(row0 + rloc + r) * 256 + col] = acc[jt][r] + bv;
    }
  }
}

// ---------------- flash attention ----------------
// 256 blocks x 512 thr (8 waves = 2/SIMD). Block = 64 q-rows; wave quads (h=w>>2)
// split KV in halves (64 iters of KVBLK=32 each), merged via LDS at the end.
// Staging: global_load_lds w16, linear LDS dest + inverse-swizzled global source.
// One barrier per iteration (STAGE(next) ; compute(cur) ; barrier).
// LDS: [h*64K: K dbuf 2x16K | V dbuf 2x16K] x2 halves | 128K..136K: P (1K/wave)
__global__ __launch_bounds__(512, 2) void attn_k(const unsigned short* __restrict__ qg,
                                                 const unsigned short* __restrict__ kg,
                                                 const unsigned short* __restrict__ vtg,
                                                 unsigned short* __restrict__ og) {
  __shared__ __align__(16) unsigned char smem[139264];
  const int tid = threadIdx.x, w = tid >> 6, l = tid & 63, g = l >> 4, c = l & 15;
  const int h = w >> 2, wi = w & 3;
  const int bid = blockIdx.x;
  const int qt = (bid & 7) * 32 + (bid >> 3);  // XCD-bijective swizzle (256 = 8*32)
  const int b4 = qt >> 6;
  const int q0 = (qt & 63) * 64;
  const size_t qrow = (size_t)b4 * 4096 + q0 + wi * 16 + c;

  u32x4 qf[8];  // Q^T B-frags: Q[q=c][ch*32 + 8g + j]
  {
    const unsigned short* qp = qg + qrow * 256;
#pragma unroll
    for (int ch = 0; ch < 8; ++ch) qf[ch] = *(const u32x4*)(qp + ch * 32 + g * 8);
  }
  f32x4 o[16];
#pragma unroll
  for (int dt = 0; dt < 16; ++dt) o[dt] = (f32x4){0.f, 0.f, 0.f, 0.f};
  float m_run = -1e30f, l_run = 0.f;

  const unsigned short* kb = kg + (size_t)b4 * 4096 * 256;
  const unsigned short* vtb = vtg + (size_t)b4 * 4096 * 256;
  const int kvbase = h * 2048;

  unsigned char* Kreg = smem + h * 65536;
  unsigned char* Vreg = smem + h * 65536 + 32768;
  unsigned char* Pb = smem + 131072 + w * 1024;
  const int spc = swz4(c);

  // per-lane constant staging offsets (ushort units); swizzle key is tile-local row
  int offk[4], offv[4], lofs[4];
#pragma unroll
  for (int j = 0; j < 4; ++j) {
    const int s = (wi * 4 + j) * 64 + l;
    const int kk = s >> 5, bl = s & 31;
    offk[j] = kk * 256 + ((bl ^ (kk & 7)) << 3);
    const int d = s >> 2, bv = s & 3;
    offv[j] = d * 4096 + ((bv ^ swz4(d)) << 3);
    lofs[j] = (wi * 4 + j) * 1024;  // wave-uniform LDS base offset (bytes)
  }

#define STAGE(buf, kv0)                                                        \
  {                                                                            \
    const int _kvo = (kv0);                                                    \
    _Pragma("unroll") for (int j = 0; j < 4; ++j)                              \
        gld16(Kreg + (buf) * 16384 + lofs[j], kb + _kvo * 256 + offk[j]);      \
    _Pragma("unroll") for (int j = 0; j < 4; ++j)                              \
        gld16(Vreg + (buf) * 16384 + lofs[j], vtb + _kvo + offv[j]);           \
  }

  STAGE(0, kvbase);
  __syncthreads();

  const float alpha = 0.09016844f;  // log2(e)/sqrt(256)
#pragma unroll 1
  for (int t = 0; t < 64; ++t) {
    const int cur = t & 1;
    if (t + 1 < 64) STAGE(1 - cur, kvbase + (t + 1) * 32);
    const unsigned char* Kb = Kreg + cur * 16384;
    const unsigned char* Vb = Vreg + cur * 16384;

    // S^T = K · Q^T : A=K rows (LDS), B=Q^T (regs). D: row=kk(4g+r), col=q(c)
    f32x4 s0 = {0.f, 0.f, 0.f, 0.f}, s1 = {0.f, 0.f, 0.f, 0.f};
#pragma unroll
    for (int ch = 0; ch < 8; ++ch) {
      const int blk = (ch << 2) | g;
      bf16x8 a0 = ldbf16(Kb + c * 512 + ((blk ^ (c & 7)) << 4));
      bf16x8 a1 = ldbf16(Kb + (16 + c) * 512 + ((blk ^ (c & 7)) << 4));
      bf16x8 bq = __builtin_bit_cast(bf16x8, qf[ch]);
      s0 = mfma16(a0, bq, s0);
      s1 = mfma16(a1, bq, s1);
    }
    // online softmax over kk (this lane's values share q=c)
    float sv[8];
#pragma unroll
    for (int r = 0; r < 4; ++r) { sv[r] = s0[r] * alpha; sv[4 + r] = s1[r] * alpha; }
    float mt = sv[0];
#pragma unroll
    for (int i = 1; i < 8; ++i) mt = fmaxf(mt, sv[i]);
    mt = fmaxf(mt, __shfl_xor(mt, 16));
    mt = fmaxf(mt, __shfl_xor(mt, 32));
    if (__any(mt > m_run + 8.f)) {  // defer-max (T13)
      const float mn = fmaxf(m_run, mt);
      const float f = exp2f(m_run - mn);
      l_run *= f;
#pragma unroll
      for (int dt = 0; dt < 16; ++dt) {
        o[dt][0] *= f; o[dt][1] *= f; o[dt][2] *= f; o[dt][3] *= f;
      }
      m_run = mn;
    }
    float p[8], ls = 0.f;
#pragma unroll
    for (int i = 0; i < 8; ++i) { p[i] = exp2f(sv[i] - m_run); ls += p[i]; }
    ls += __shfl_xor(ls, 16);
    ls += __shfl_xor(ls, 32);
    l_run += ls;

    // P -> LDS [q=16][kk=32] bf16 (per-wave region, intra-wave RAW only)
    us16x4 w0, w1;
    w0[0] = f2bf(p[0]); w0[1] = f2bf(p[1]); w0[2] = f2bf(p[2]); w0[3] = f2bf(p[3]);
    w1[0] = f2bf(p[4]); w1[1] = f2bf(p[5]); w1[2] = f2bf(p[6]); w1[3] = f2bf(p[7]);
    *(us16x4*)(Pb + c * 64 + (((g >> 1) ^ spc) << 4) + ((g & 1) << 3)) = w0;
    *(us16x4*)(Pb + c * 64 + (((2 + (g >> 1)) ^ spc) << 4) + ((g & 1) << 3)) = w1;
    bf16x8 bp = ldbf16(Pb + c * 64 + ((g ^ spc) << 4));  // B[kk=8g+j][q=c]

    // O^T += V^T · P : A=Vt rows d (LDS), B=P. D: row=d(4g+r), col=q(c)
#pragma unroll
    for (int dt = 0; dt < 16; ++dt) {
      const int d = dt * 16 + c;
      bf16x8 av = ldbf16(Vb + d * 64 + ((g ^ swz4(d)) << 4));
      o[dt] = mfma16(av, bp, o[dt]);
    }
    __syncthreads();
  }
#undef STAGE

  // merge the two KV halves (wave wi+4 -> wave wi), LDS area reuses K/V space
  float* mrg = (float*)smem;  // 4 waves x 64 lanes x 67 f32 = 68608 B
  if (h == 1) {
    float* mb = mrg + (size_t)(wi * 64 + l) * 67;
#pragma unroll
    for (int dt = 0; dt < 16; ++dt) {
      mb[dt * 4 + 0] = o[dt][0]; mb[dt * 4 + 1] = o[dt][1];
      mb[dt * 4 + 2] = o[dt][2]; mb[dt * 4 + 3] = o[dt][3];
    }
    mb[64] = m_run; mb[65] = l_run;
  }
  __syncthreads();
  if (h == 0) {
    const float* mb = mrg + (size_t)(wi * 64 + l) * 67;
    const float m1 = mb[64], l1 = mb[65];
    const float mn = fmaxf(m_run, m1);
    const float f0 = exp2f(m_run - mn), f1 = exp2f(m1 - mn);
    const float inv = 1.f / (f0 * l_run + f1 * l1);
    unsigned short* op = og + qrow * 256;
#pragma unroll
    for (int dt = 0; dt < 16; ++dt) {
      us16x4 pk;
      pk[0] = f2bf((f0 * o[dt][0] + f1 * mb[dt * 4 + 0]) * inv);
      pk[1] = f2bf((f0 * o[dt][1] + f1 * mb[dt * 4 + 1]) * inv);
      pk[2] = f2bf((f0 * o[dt][2] + f1 * mb[dt * 4 + 2]) * inv);
      pk[3] = f2bf((f0 * o[dt][3] + f1 * mb[dt * 4 + 3]) * inv);
      *(us16x4*)(op + dt * 16 + (g << 2)) = pk;  // 4 consecutive d, 8B store
    }
  }
}

extern "C" void kernel_launch(void* const* d_in, const int* in_sizes, int n_in,
                              void* d_out, int out_size, void* d_ws, size_t ws_size,
                              hipStream_t stream) {
  (void)in_sizes; (void)n_in; (void)out_size; (void)ws_size;
  const float* desc0 = (const float*)d_in[0];
  const float* desc1 = (const float*)d_in[1];
  const float* Wq = (const float*)d_in[2];
  const float* bq = (const float*)d_in[3];
  const float* Wk = (const float*)d_in[4];
  const float* bk = (const float*)d_in[5];
  const float* Wv = (const float*)d_in[6];
  const float* bv = (const float*)d_in[7];
  const float* Wo = (const float*)d_in[8];
  const float* bo = (const float*)d_in[9];

  unsigned char* ws = (unsigned char*)d_ws;
  unsigned short* qw = (unsigned short*)(ws);
  unsigned short* kw = (unsigned short*)(ws + 8388608);
  unsigned short* vtw = (unsigned short*)(ws + 16777216);
  unsigned short* aw = (unsigned short*)(ws + 25165824);

  proj_k<0, 0><<<1024, 256, 0, stream>>>(desc0, Wq, bq, qw);
  proj_k<0, 0><<<1024, 256, 0, stream>>>(desc1, Wk, bk, kw);
  proj_k<0, 1><<<1024, 256, 0, stream>>>(desc1, Wv, bv, vtw);
  attn_k<<<256, 512, 0, stream>>>(qw, kw, vtw, aw);
  proj_k<1, 2><<<1024, 256, 0, stream>>>(aw, Wo, bo, (float*)d_out);
}